// Round 10
// baseline (837.320 us; speedup 1.0000x reference)
//
#include <hip/hip_runtime.h>

// GCNConv(100k nodes, 1M edges, D=128) + two heads (128->64), fp32 in/out.
// R18: persistent mega-kernel, barrier pathology fixed + atomic-free scatter.
//  - R16/R17 post-mortem: both moved identical bytes; the ~500us was barrier
//    fabric-flooding (R16: 16k spin-RMWs/us on one line queueing ahead of
//    arrivals; R17: buffer_inv PER POLL from acquire agent loads, nuking
//    every XCD L2 while stragglers worked). Fix: RMW poll at s_sleep(127)
//    (~3.4us cadence, 64x less pressure), fences once per block per barrier.
//  - ALL far atomics eliminated: scatter offsets are exact, precomputed by
//    per-block hist rows (P1) + per-bucket scan (P2). Layouts are
//    block-exclusive rows (no cross-XCD line write-sharing on metadata).
// Phases (5 software grid barriers):
//   P1 per-block bucket histogram row || WfT fp16 fusion (blk 0-15) || bias (16)
//   P2 per-bucket exclusive scan over 1024 block-hists -> off_g + totals
//   P3 scatter: LDS cursors = SLOT base + own offsets; packed 4B ebuf writes
//   P4 per-bucket counting sort -> csr + off2; xh[i] = fp16(dinv_i * x[i])
//   P5 gather: one wave/node, pure row-sum (prescaled xh), 8 rows in flight
//   P6 MFMA fp16 GEMM out = aggh @ WfT^T + bf (782 tiles)

#define GRID 1024
#define GPAD 1040        // off_g row stride (ints): 1024 offsets + total + pad
#define BLOCK 256
#define NB_MAX 800       // max buckets (n <= 102400), also hist row stride
#define SLOT 2048        // per-bucket ebuf/csr capacity (avg 1280)

typedef _Float16 half8 __attribute__((ext_vector_type(8)));
typedef _Float16 half4 __attribute__((ext_vector_type(4)));
typedef _Float16 half2v __attribute__((ext_vector_type(2)));
typedef float f32x4 __attribute__((ext_vector_type(4)));

__device__ inline void gsync(int* bar, int target) {
    __syncthreads();
    if (threadIdx.x == 0) {
        __threadfence();                       // release: wbl2 once
        atomicAdd(bar, 1);                     // arrival
        while (atomicAdd(bar, 0) < target)     // coherent RMW poll,
            __builtin_amdgcn_s_sleep(127);     // ~3.4us cadence (was 128cy!)
        __threadfence();                       // acquire: inv once
    }
    __syncthreads();
}

__global__ __launch_bounds__(BLOCK, 4) void k_mega(
    const float* __restrict__ x, const int* __restrict__ src,
    const int* __restrict__ dst, int E,
    const float* __restrict__ Wg, const float* __restrict__ Wh,
    const float* __restrict__ Wl, const float* __restrict__ bg,
    const float* __restrict__ bh, const float* __restrict__ bl,
    _Float16* __restrict__ WfT, float* __restrict__ bf,
    int* __restrict__ bar, int* __restrict__ hist_g, int* __restrict__ off_g,
    int* __restrict__ ebuf, int* __restrict__ csr, int2* __restrict__ off2,
    _Float16* __restrict__ xh, _Float16* __restrict__ aggh,
    float* __restrict__ out, int n, int NB) {
    __shared__ int smem[NB_MAX];
    int t = threadIdx.x;
    int bid = blockIdx.x;
    int tid = bid * BLOCK + t;
    int lane = t & 63;
    int chunk = (E + GRID - 1) / GRID;
    int e0 = bid * chunk, e1 = min(E, e0 + chunk);

    // ---------------- P1: per-block hist row || WfT || bias ----------------
    for (int i = t; i < NB; i += BLOCK) smem[i] = 0;
    __syncthreads();
    for (int e = e0 + t; e < e1; e += BLOCK)
        atomicAdd(&smem[dst[e] >> 7], 1);              // LDS atomics only
    __syncthreads();
    for (int i = t; i < NB; i += BLOCK)
        hist_g[(size_t)bid * NB_MAX + i] = smem[i];    // block-exclusive row
    if (bid < 16) {  // Wf = Wg @ [Wh|Wl], stored transposed fp16: WfT[c][k]
        int r = bid * 8 + (t >> 5);
        int c0 = (t & 31) * 4;
        float a0 = 0.f, a1 = 0.f, a2 = 0.f, a3 = 0.f;
        for (int j = 0; j < 128; j++) {
            float wg = Wg[r * 128 + j];
            float4 wc;
            if (c0 < 64) wc = *(const float4*)(Wh + j * 64 + c0);
            else         wc = *(const float4*)(Wl + j * 64 + (c0 - 64));
            a0 += wg * wc.x; a1 += wg * wc.y; a2 += wg * wc.z; a3 += wg * wc.w;
        }
        WfT[(size_t)(c0 + 0) * 128 + r] = (_Float16)a0;
        WfT[(size_t)(c0 + 1) * 128 + r] = (_Float16)a1;
        WfT[(size_t)(c0 + 2) * 128 + r] = (_Float16)a2;
        WfT[(size_t)(c0 + 3) * 128 + r] = (_Float16)a3;
    } else if (bid == 16) {
        int c = t;
        if (c < 128) {
            float acc = (c < 64) ? bh[c] : bl[c - 64];
            for (int j = 0; j < 128; j++) {
                float wc = (c < 64) ? Wh[j * 64 + c] : Wl[j * 64 + (c - 64)];
                acc += bg[j] * wc;
            }
            bf[c] = acc;
        }
    }
    gsync(bar, GRID);

    // ---------------- P2: per-bucket exclusive scan over GRID hists ----------------
    if (bid < NB) {
        int h0 = hist_g[(size_t)(t * 4 + 0) * NB_MAX + bid];
        int h1 = hist_g[(size_t)(t * 4 + 1) * NB_MAX + bid];
        int h2 = hist_g[(size_t)(t * 4 + 2) * NB_MAX + bid];
        int h3 = hist_g[(size_t)(t * 4 + 3) * NB_MAX + bid];
        int p = h0 + h1 + h2 + h3;
        __syncthreads();
        smem[t] = p;
        __syncthreads();
        for (int ofs = 1; ofs < BLOCK; ofs <<= 1) {
            int v = (t >= ofs) ? smem[t - ofs] : 0;
            __syncthreads();
            smem[t] += v;
            __syncthreads();
        }
        int ex = smem[t] - p;                           // exclusive
        size_t rb = (size_t)bid * GPAD;                 // block-exclusive row
        off_g[rb + t * 4 + 0] = ex;
        off_g[rb + t * 4 + 1] = ex + h0;
        off_g[rb + t * 4 + 2] = ex + h0 + h1;
        off_g[rb + t * 4 + 3] = ex + h0 + h1 + h2;
        if (t == BLOCK - 1) off_g[rb + GRID] = ex + p;  // bucket total
    }
    gsync(bar, 2 * GRID);

    // ---------------- P3: scatter (LDS cursors, zero global atomics) ----------------
    for (int i = t; i < NB; i += BLOCK)
        smem[i] = i * SLOT + off_g[(size_t)i * GPAD + bid];
    __syncthreads();
    for (int e = e0 + t; e < e1; e += BLOCK) {
        int d = dst[e];
        int pos = atomicAdd(&smem[d >> 7], 1);          // LDS cursor
        ebuf[pos] = src[e] | ((d & 127) << 20);         // packed 4B/edge
    }
    gsync(bar, 3 * GRID);

    // ---------------- P4: counting sort -> csr/off2 + scaled convert ----------------
    if (bid < NB) {
        int* cntL = smem;
        int* preL = smem + 128;
        int* curL = smem + 256;
        int node0 = bid << 7;
        int nn = min(128, n - node0);
        int eb0 = bid * SLOT;
        int eb1 = eb0 + off_g[(size_t)bid * GPAD + GRID];
        if (t < 128) cntL[t] = 0;
        __syncthreads();
        for (int e = eb0 + t; e < eb1; e += BLOCK)
            atomicAdd(&cntL[(ebuf[e] >> 20) & 127], 1);
        __syncthreads();
        if (t < 128) preL[t] = cntL[t];
        __syncthreads();
        for (int ofs = 1; ofs < 128; ofs <<= 1) {
            int v = (t < 128 && t >= ofs) ? preL[t - ofs] : 0;
            __syncthreads();
            if (t < 128) preL[t] += v;
            __syncthreads();
        }
        if (t < 128) curL[t] = preL[t] - cntL[t];
        __syncthreads();
        if (t < nn) off2[node0 + t] = make_int2(eb0 + curL[t], eb0 + preL[t]);
        for (int e = eb0 + t; e < eb1; e += BLOCK) {
            int p = ebuf[e];
            int pos = atomicAdd(&curL[(p >> 20) & 127], 1);
            csr[eb0 + pos] = p & 0xFFFFF;
        }
        const float4* xr = (const float4*)(x + (size_t)node0 * 128);
        half4* xw = (half4*)(xh + (size_t)node0 * 128);
        for (int idx = t; idx < nn * 32; idx += BLOCK) {
            int row = idx >> 5;
            float dvL = rsqrtf((float)(cntL[row] + 1));
            float4 v = xr[idx];
            half4 o;
            o.x = (_Float16)(dvL * v.x); o.y = (_Float16)(dvL * v.y);
            o.z = (_Float16)(dvL * v.z); o.w = (_Float16)(dvL * v.w);
            xw[idx] = o;
        }
    }
    gsync(bar, 4 * GRID);

    // ---------------- P5: gather (one wave per node, pure row-sum) ----------------
    {
        int gw = tid >> 6;
        const int NW = (GRID * BLOCK) >> 6;
        for (int d = gw; d < n; d += NW) {
            int2 oe = off2[d];
            int beg = oe.x, end = oe.y;
            float dv = rsqrtf((float)(end - beg + 1));
            half2v sv = ((const half2v*)(xh + (size_t)d * 128))[lane];
            float ax = (float)sv.x, ay = (float)sv.y;
            for (int base = beg; base < end; base += 64) {
                int cnt = min(64, end - base);
                int s = 0;
                if (lane < cnt) s = csr[base + lane];
                int j = 0;
                for (; j + 8 <= cnt; j += 8) {
                    int s0 = __shfl(s, j);
                    int s1 = __shfl(s, j + 1);
                    int s2 = __shfl(s, j + 2);
                    int s3 = __shfl(s, j + 3);
                    int s4 = __shfl(s, j + 4);
                    int s5 = __shfl(s, j + 5);
                    int s6 = __shfl(s, j + 6);
                    int s7 = __shfl(s, j + 7);
                    half2v v0 = ((const half2v*)(xh + (size_t)s0 * 128))[lane];
                    half2v v1 = ((const half2v*)(xh + (size_t)s1 * 128))[lane];
                    half2v v2 = ((const half2v*)(xh + (size_t)s2 * 128))[lane];
                    half2v v3 = ((const half2v*)(xh + (size_t)s3 * 128))[lane];
                    half2v v4 = ((const half2v*)(xh + (size_t)s4 * 128))[lane];
                    half2v v5 = ((const half2v*)(xh + (size_t)s5 * 128))[lane];
                    half2v v6 = ((const half2v*)(xh + (size_t)s6 * 128))[lane];
                    half2v v7 = ((const half2v*)(xh + (size_t)s7 * 128))[lane];
                    ax += (float)v0.x + (float)v1.x + (float)v2.x + (float)v3.x
                        + (float)v4.x + (float)v5.x + (float)v6.x + (float)v7.x;
                    ay += (float)v0.y + (float)v1.y + (float)v2.y + (float)v3.y
                        + (float)v4.y + (float)v5.y + (float)v6.y + (float)v7.y;
                }
                for (; j + 4 <= cnt; j += 4) {
                    int s0 = __shfl(s, j);
                    int s1 = __shfl(s, j + 1);
                    int s2 = __shfl(s, j + 2);
                    int s3 = __shfl(s, j + 3);
                    half2v v0 = ((const half2v*)(xh + (size_t)s0 * 128))[lane];
                    half2v v1 = ((const half2v*)(xh + (size_t)s1 * 128))[lane];
                    half2v v2 = ((const half2v*)(xh + (size_t)s2 * 128))[lane];
                    half2v v3 = ((const half2v*)(xh + (size_t)s3 * 128))[lane];
                    ax += (float)v0.x + (float)v1.x + (float)v2.x + (float)v3.x;
                    ay += (float)v0.y + (float)v1.y + (float)v2.y + (float)v3.y;
                }
                for (; j < cnt; j++) {
                    int s0 = __shfl(s, j);
                    half2v v0 = ((const half2v*)(xh + (size_t)s0 * 128))[lane];
                    ax += (float)v0.x;
                    ay += (float)v0.y;
                }
            }
            half2v o;
            o.x = (_Float16)(dv * ax);
            o.y = (_Float16)(dv * ay);
            ((half2v*)(aggh + (size_t)d * 128))[lane] = o;
        }
    }
    gsync(bar, 5 * GRID);

    // ---------------- P6: MFMA fp16 GEMM, one 128-row tile per block ----------------
    {
        int ntiles = (n + 127) >> 7;
        if (bid < ntiles) {
            int wave = t >> 6;
            int l15 = lane & 15;
            int lk = lane >> 4;
            int row_base = bid * 128 + wave * 32;

            half8 a[2][4];
#pragma unroll
            for (int rf = 0; rf < 2; rf++) {
                int r = row_base + rf * 16 + l15;
                if (r >= n) r = n - 1;
                const _Float16* ap = aggh + (size_t)r * 128 + lk * 8;
#pragma unroll
                for (int kk = 0; kk < 4; kk++)
                    a[rf][kk] = *(const half8*)(ap + kk * 32);
            }

            f32x4 acc[2][8];
#pragma unroll
            for (int rf = 0; rf < 2; rf++)
#pragma unroll
                for (int cf = 0; cf < 8; cf++)
                    acc[rf][cf] = (f32x4){0.f, 0.f, 0.f, 0.f};

#pragma unroll
            for (int kk = 0; kk < 4; kk++) {
#pragma unroll
                for (int cf = 0; cf < 8; cf++) {
                    const _Float16* bp = WfT + (size_t)(cf * 16 + l15) * 128 + kk * 32 + lk * 8;
                    half8 bfr = *(const half8*)bp;
#pragma unroll
                    for (int rf = 0; rf < 2; rf++)
                        acc[rf][cf] = __builtin_amdgcn_mfma_f32_16x16x32_f16(
                            a[rf][kk], bfr, acc[rf][cf], 0, 0, 0);
                }
            }

#pragma unroll
            for (int cf = 0; cf < 8; cf++) {
                int c = cf * 16 + l15;
                float bv = bf[c];
                size_t cbase = (c < 64) ? (size_t)c : (size_t)n * 64 + (size_t)(c - 64);
#pragma unroll
                for (int rf = 0; rf < 2; rf++) {
                    int r0 = row_base + rf * 16 + lk * 4;
#pragma unroll
                    for (int j = 0; j < 4; j++) {
                        int r = r0 + j;
                        if (r < n) out[cbase + (size_t)r * 64] = acc[rf][cf][j] + bv;
                    }
                }
            }
        }
    }
}

extern "C" void kernel_launch(void* const* d_in, const int* in_sizes, int n_in,
                              void* d_out, int out_size, void* d_ws, size_t ws_size,
                              hipStream_t stream) {
    const float* x  = (const float*)d_in[0];
    const int*   ei = (const int*)d_in[1];
    const float* Wg = (const float*)d_in[2];
    const float* bg = (const float*)d_in[3];
    const float* Wh = (const float*)d_in[4];
    const float* bh = (const float*)d_in[5];
    const float* Wl = (const float*)d_in[6];
    const float* bl = (const float*)d_in[7];
    float* out = (float*)d_out;

    int n = in_sizes[0] / 128;
    int E = in_sizes[1] / 2;
    const int* src = ei;
    const int* dst = ei + E;
    int NB = (n + 127) >> 7;

#define WS_TAKE(ptr, type, count)                                        \
    ptr = (type*)wsp;                                                    \
    wsp = (char*)(((size_t)(wsp + (size_t)(count) * sizeof(type)) + 255) \
                  & ~(size_t)255)

    char* wsp = (char*)d_ws;
    int*      bar;    WS_TAKE(bar,    int,      64);
    int*      hist_g; WS_TAKE(hist_g, int,      (size_t)GRID * NB_MAX);
    int*      off_g;  WS_TAKE(off_g,  int,      (size_t)NB_MAX * GPAD);
    int*      ebuf;   WS_TAKE(ebuf,   int,      (size_t)NB_MAX * SLOT);
    int*      csr;    WS_TAKE(csr,    int,      (size_t)NB_MAX * SLOT);
    int2*     off2;   WS_TAKE(off2,   int2,     n);
    _Float16* WfT;    WS_TAKE(WfT,    _Float16, 128 * 128);
    float*    bfp;    WS_TAKE(bfp,    float,    128);
    _Float16* xh;     WS_TAKE(xh,     _Float16, (size_t)n * 128);
    _Float16* aggh;   WS_TAKE(aggh,   _Float16, (size_t)n * 128);

    hipMemsetAsync(bar, 0, 256, stream);
    k_mega<<<GRID, BLOCK, 0, stream>>>(
        x, src, dst, E, Wg, Wh, Wl, bg, bh, bl, WfT, bfp,
        bar, hist_g, off_g, ebuf, csr, off2, xh, aggh, out, n, NB);
}

// Round 11
// 280.635 us; speedup vs baseline: 2.9837x; 2.9837x over previous
//
#include <hip/hip_runtime.h>

// GCNConv(100k nodes, 1M edges, D=128) + two heads (128->64), fp32 in/out.
// R19: split pipeline + the two validated mega-kernel discoveries.
//  - Software grid barriers ABANDONED (R16-R18: ~150us/barrier regardless of
//    spin mechanism; phases sum ~90us but mega-kernels land 560-760us).
//  - Direct-slot scatter (validated in R16 P1): pos=atomicAdd(&cnt[d],1),
//    csr[d*64+pos]=src[e]. Deletes bucket/ebuf/counting-sort machinery
//    (R14's top kernel, 46us at 9% occupancy) AND the k_node dispatch.
//  - Unscaled fp16 xh + on-the-fly weights (validated in R17 P2): convert
//    has no degree dependence -> folds into k_prep next to the scatter;
//    gather computes w=rsqrt(cnt[s]+1) from the 400KB L2-resident cnt.
// Pipeline (4 dispatches): memset(cnt) -> k_prep(scatter|convert|WfT|bias)
//           -> k_gather(wave/node, 8 rows in flight) -> k_final(MFMA fp16).

#define BLOCK 256
#define SCAT 2048        // scatter/convert blocks in k_prep
#define SLOTN 64         // per-node csr slot (Poisson(10): P(deg>64) ~ 1e-40)

typedef _Float16 half8 __attribute__((ext_vector_type(8)));
typedef _Float16 half4 __attribute__((ext_vector_type(4)));
typedef _Float16 half2v __attribute__((ext_vector_type(2)));
typedef float f32x4 __attribute__((ext_vector_type(4)));

// ---------------- prep: direct-slot scatter + x->fp16 || WfT || bias ----------------

__global__ __launch_bounds__(BLOCK) void k_prep(
    const float* __restrict__ x, const int* __restrict__ src,
    const int* __restrict__ dst, int E,
    const float* __restrict__ Wg, const float* __restrict__ Wh,
    const float* __restrict__ Wl, const float* __restrict__ bg,
    const float* __restrict__ bh, const float* __restrict__ bl,
    _Float16* __restrict__ WfT, float* __restrict__ bf,
    int* __restrict__ cnt, int* __restrict__ csr,
    _Float16* __restrict__ xh, int n) {
    int b = blockIdx.x;
    int t = threadIdx.x;
    if (b < 16) {  // Wf = Wg @ [Wh|Wl], stored transposed fp16: WfT[c][k]
        int r = b * 8 + (t >> 5);
        int c0 = (t & 31) * 4;
        float a0 = 0.f, a1 = 0.f, a2 = 0.f, a3 = 0.f;
        for (int j = 0; j < 128; j++) {
            float wg = Wg[r * 128 + j];
            float4 wc;
            if (c0 < 64) wc = *(const float4*)(Wh + j * 64 + c0);
            else         wc = *(const float4*)(Wl + j * 64 + (c0 - 64));
            a0 += wg * wc.x; a1 += wg * wc.y; a2 += wg * wc.z; a3 += wg * wc.w;
        }
        WfT[(size_t)(c0 + 0) * 128 + r] = (_Float16)a0;
        WfT[(size_t)(c0 + 1) * 128 + r] = (_Float16)a1;
        WfT[(size_t)(c0 + 2) * 128 + r] = (_Float16)a2;
        WfT[(size_t)(c0 + 3) * 128 + r] = (_Float16)a3;
    } else if (b == 16) {  // bias fusion
        int c = t;
        if (c < 128) {
            float acc = (c < 64) ? bh[c] : bl[c - 64];
            for (int j = 0; j < 128; j++) {
                float wc = (c < 64) ? Wh[j * 64 + c] : Wl[j * 64 + (c - 64)];
                acc += bg[j] * wc;
            }
            bf[c] = acc;
        }
    } else {
        int blk = b - 17;
        // direct-slot edge scatter (device atomics; cnt is 400KB, L2-resident)
        for (int e = blk * BLOCK + t; e < E; e += (SCAT - 0) * BLOCK) {
            int d = dst[e];
            int pos = atomicAdd(&cnt[d], 1);
            if (pos < SLOTN) csr[(size_t)d * SLOTN + pos] = src[e];
        }
        // x -> fp16 (UNSCALED: no degree dependence)
        int total4 = n * 32;
        const float4* xr = (const float4*)x;
        half4* xw = (half4*)xh;
        for (int idx = blk * BLOCK + t; idx < total4; idx += SCAT * BLOCK) {
            float4 v = xr[idx];
            half4 o;
            o.x = (_Float16)v.x; o.y = (_Float16)v.y;
            o.z = (_Float16)v.z; o.w = (_Float16)v.w;
            xw[idx] = o;
        }
    }
}

// ---------------- gather: one wave per node, weights on the fly ----------------
// aggh[d] = fp16( dv * (sum_j dinv[s_j]*xh[s_j] + dv*xh[d]) ), dv=rsqrt(deg+1).
// Per 64-neighbor batch: one coalesced csr load, one batched cnt[s] load ->
// w=rsqrt(cnt+1); (s,w) shuffles; 8 independent 256B row reads in flight.

__global__ __launch_bounds__(BLOCK) void k_gather(const int* __restrict__ cnt,
                                                  const int* __restrict__ csr,
                                                  const _Float16* __restrict__ xh,
                                                  _Float16* __restrict__ aggh, int n) {
    int wave = (blockIdx.x * blockDim.x + threadIdx.x) >> 6;
    int lane = threadIdx.x & 63;
    if (wave >= n) return;
    int d = wave;
    int deg = cnt[d];
    int degc = min(deg, SLOTN);
    float dv = rsqrtf((float)(deg + 1));

    int s = 0; float w = 0.f;
    if (lane < degc) {
        s = csr[(size_t)d * SLOTN + lane];          // coalesced 256B batch
        w = rsqrtf((float)(cnt[s] + 1));            // cnt L2-resident
    }
    half2v xv = ((const half2v*)(xh + (size_t)d * 128))[lane];  // self
    float ax = dv * (float)xv.x, ay = dv * (float)xv.y;

    int j = 0;
    for (; j + 8 <= degc; j += 8) {
        int s0 = __shfl(s, j);     float w0 = __shfl(w, j);
        int s1 = __shfl(s, j + 1); float w1 = __shfl(w, j + 1);
        int s2 = __shfl(s, j + 2); float w2 = __shfl(w, j + 2);
        int s3 = __shfl(s, j + 3); float w3 = __shfl(w, j + 3);
        int s4 = __shfl(s, j + 4); float w4 = __shfl(w, j + 4);
        int s5 = __shfl(s, j + 5); float w5 = __shfl(w, j + 5);
        int s6 = __shfl(s, j + 6); float w6 = __shfl(w, j + 6);
        int s7 = __shfl(s, j + 7); float w7 = __shfl(w, j + 7);
        half2v v0 = ((const half2v*)(xh + (size_t)s0 * 128))[lane];
        half2v v1 = ((const half2v*)(xh + (size_t)s1 * 128))[lane];
        half2v v2 = ((const half2v*)(xh + (size_t)s2 * 128))[lane];
        half2v v3 = ((const half2v*)(xh + (size_t)s3 * 128))[lane];
        half2v v4 = ((const half2v*)(xh + (size_t)s4 * 128))[lane];
        half2v v5 = ((const half2v*)(xh + (size_t)s5 * 128))[lane];
        half2v v6 = ((const half2v*)(xh + (size_t)s6 * 128))[lane];
        half2v v7 = ((const half2v*)(xh + (size_t)s7 * 128))[lane];
        ax += w0 * (float)v0.x + w1 * (float)v1.x + w2 * (float)v2.x
            + w3 * (float)v3.x + w4 * (float)v4.x + w5 * (float)v5.x
            + w6 * (float)v6.x + w7 * (float)v7.x;
        ay += w0 * (float)v0.y + w1 * (float)v1.y + w2 * (float)v2.y
            + w3 * (float)v3.y + w4 * (float)v4.y + w5 * (float)v5.y
            + w6 * (float)v6.y + w7 * (float)v7.y;
    }
    for (; j + 4 <= degc; j += 4) {
        int s0 = __shfl(s, j);     float w0 = __shfl(w, j);
        int s1 = __shfl(s, j + 1); float w1 = __shfl(w, j + 1);
        int s2 = __shfl(s, j + 2); float w2 = __shfl(w, j + 2);
        int s3 = __shfl(s, j + 3); float w3 = __shfl(w, j + 3);
        half2v v0 = ((const half2v*)(xh + (size_t)s0 * 128))[lane];
        half2v v1 = ((const half2v*)(xh + (size_t)s1 * 128))[lane];
        half2v v2 = ((const half2v*)(xh + (size_t)s2 * 128))[lane];
        half2v v3 = ((const half2v*)(xh + (size_t)s3 * 128))[lane];
        ax += w0 * (float)v0.x + w1 * (float)v1.x
            + w2 * (float)v2.x + w3 * (float)v3.x;
        ay += w0 * (float)v0.y + w1 * (float)v1.y
            + w2 * (float)v2.y + w3 * (float)v3.y;
    }
    for (; j < degc; j++) {
        int s0 = __shfl(s, j); float w0 = __shfl(w, j);
        half2v v0 = ((const half2v*)(xh + (size_t)s0 * 128))[lane];
        ax += w0 * (float)v0.x;
        ay += w0 * (float)v0.y;
    }
    half2v o;
    o.x = (_Float16)(dv * ax);
    o.y = (_Float16)(dv * ay);
    ((half2v*)(aggh + (size_t)d * 128))[lane] = o;
}

// ---------------- final GEMM via MFMA fp16: out = aggh @ WfT^T + bf ----------------

__global__ __launch_bounds__(BLOCK) void k_final(const _Float16* __restrict__ aggh,
                                                 const _Float16* __restrict__ WfT,
                                                 const float* __restrict__ bf,
                                                 float* __restrict__ out, int n) {
    int wave = threadIdx.x >> 6;          // 0..3
    int lane = threadIdx.x & 63;
    int l15 = lane & 15;
    int lk = lane >> 4;                   // 0..3
    int row_base = blockIdx.x * 128 + wave * 32;

    half8 a[2][4];
#pragma unroll
    for (int rf = 0; rf < 2; rf++) {
        int r = row_base + rf * 16 + l15;
        if (r >= n) r = n - 1;
        const _Float16* ap = aggh + (size_t)r * 128 + lk * 8;
#pragma unroll
        for (int kk = 0; kk < 4; kk++)
            a[rf][kk] = *(const half8*)(ap + kk * 32);
    }

    f32x4 acc[2][8];
#pragma unroll
    for (int rf = 0; rf < 2; rf++)
#pragma unroll
        for (int cf = 0; cf < 8; cf++)
            acc[rf][cf] = (f32x4){0.f, 0.f, 0.f, 0.f};

#pragma unroll
    for (int kk = 0; kk < 4; kk++) {
#pragma unroll
        for (int cf = 0; cf < 8; cf++) {
            const _Float16* bp = WfT + (size_t)(cf * 16 + l15) * 128 + kk * 32 + lk * 8;
            half8 bfr = *(const half8*)bp;
#pragma unroll
            for (int rf = 0; rf < 2; rf++)
                acc[rf][cf] = __builtin_amdgcn_mfma_f32_16x16x32_f16(
                    a[rf][kk], bfr, acc[rf][cf], 0, 0, 0);
        }
    }

#pragma unroll
    for (int cf = 0; cf < 8; cf++) {
        int c = cf * 16 + l15;
        float bv = bf[c];
        size_t cbase = (c < 64) ? (size_t)c : (size_t)n * 64 + (size_t)(c - 64);
#pragma unroll
        for (int rf = 0; rf < 2; rf++) {
            int r0 = row_base + rf * 16 + lk * 4;
#pragma unroll
            for (int j = 0; j < 4; j++) {
                int r = r0 + j;
                if (r < n) out[cbase + (size_t)r * 64] = acc[rf][cf][j] + bv;
            }
        }
    }
}

extern "C" void kernel_launch(void* const* d_in, const int* in_sizes, int n_in,
                              void* d_out, int out_size, void* d_ws, size_t ws_size,
                              hipStream_t stream) {
    const float* x  = (const float*)d_in[0];
    const int*   ei = (const int*)d_in[1];
    const float* Wg = (const float*)d_in[2];
    const float* bg = (const float*)d_in[3];
    const float* Wh = (const float*)d_in[4];
    const float* bh = (const float*)d_in[5];
    const float* Wl = (const float*)d_in[6];
    const float* bl = (const float*)d_in[7];
    float* out = (float*)d_out;

    int n = in_sizes[0] / 128;
    int E = in_sizes[1] / 2;
    const int* src = ei;
    const int* dst = ei + E;

#define WS_TAKE(ptr, type, count)                                        \
    ptr = (type*)wsp;                                                    \
    wsp = (char*)(((size_t)(wsp + (size_t)(count) * sizeof(type)) + 255) \
                  & ~(size_t)255)

    char* wsp = (char*)d_ws;
    int*      cnt;  WS_TAKE(cnt,  int,      n);
    int*      csr;  WS_TAKE(csr,  int,      (size_t)n * SLOTN);
    _Float16* WfT;  WS_TAKE(WfT,  _Float16, 128 * 128);
    float*    bfp;  WS_TAKE(bfp,  float,    128);
    _Float16* xh;   WS_TAKE(xh,   _Float16, (size_t)n * 128);
    _Float16* aggh; WS_TAKE(aggh, _Float16, (size_t)n * 128);

    hipMemsetAsync(cnt, 0, (size_t)n * 4, stream);
    k_prep<<<17 + SCAT, BLOCK, 0, stream>>>(
        x, src, dst, E, Wg, Wh, Wl, bg, bh, bl, WfT, bfp, cnt, csr, xh, n);
    k_gather<<<((size_t)n * 64 + BLOCK - 1) / BLOCK, BLOCK, 0, stream>>>(
        cnt, csr, xh, aggh, n);
    k_final<<<(n + 127) / 128, BLOCK, 0, stream>>>(aggh, WfT, bfp, out, n);
}